// Round 5
// baseline (325.386 us; speedup 1.0000x reference)
//
#include <hip/hip_runtime.h>
#include <hip/hip_bf16.h>

typedef float f4v __attribute__((ext_vector_type(4)));
typedef short s8v __attribute__((ext_vector_type(8)));

#define TT 128
#define II 28
#define HH 200
#define BB 16     // batch rows per block
#define NT 128    // 2 waves per block
#define SH 232    // Hs row stride (bf16): 464 B rows, 16B-aligned; 116 words %32=20
#define KX 224    // combined-K offset of the x block (kc7 = K 224..255)
#define SF 212    // Hf row stride (fp32)

// pack 2 f32 -> 2 bf16 (RNE) in one dword (v_cvt_pk_bf16_f32); union pun since
// __hip_bfloat162 is not trivially copyable (no __builtin_bit_cast).
__device__ __forceinline__ int pk_bf16(float a, float b) {
    union { __hip_bfloat162 h; int i; } u;
    u.h = __float22bfloat162_rn(make_float2(a, b));
    return u.i;
}
__device__ __forceinline__ short f2bf(float f) {
    union { __hip_bfloat16 h; short s; } u;
    u.h = __float2bfloat16(f);
    return u.s;
}

__global__ __launch_bounds__(NT, 1)
void rnn_w2(const float* __restrict__ x,
            const float* __restrict__ W_ih,
            const float* __restrict__ W_hh,
            const float* __restrict__ b_ih,
            const float* __restrict__ b_hh,
            const float* __restrict__ W_fc,
            const float* __restrict__ b_fc,
            float* __restrict__ out)
{
    // LDS: Hs 2*16*232*2 = 14848 B + Hf 16*212*4 = 13568 B  => 28.4 KB
    __shared__ __align__(16) short Hs[2][BB][SH]; // bf16 h: cols 0..199, pad 200..231 = 0
    __shared__ __align__(16) float Hf[BB][SF];    // final h fp32 for FC

    const int tid  = threadIdx.x;
    const int lane = tid & 63;
    const int q    = lane >> 4;   // quad 0..3
    const int lr   = lane & 15;   // A: j-in-tile ; B/C: batch row
    const int wave = tid >> 6;    // 0..1
    const int b0   = blockIdx.x * BB;

    // j-tile split over 2 waves: wave0 -> jt 0..6, wave1 -> jt 7..12
    const int first = wave * 7;
    const int cnt   = wave ? 6 : 7;

    // zero both h buffers (h0 = 0, pads = 0)
    for (int i = tid; i < 2 * BB * SH / 2; i += NT) ((int*)Hs)[i] = 0;

    // ---- W~ fragments resident in registers (unified VGPR/AGPR, 1 wave/SIMD) ----
    // A-frag(u,kc): lane holds W~[j=16*(first+u)+lr][k=32*kc+8*q+i], i=0..7
    // W~[j][k] = W_hh[j][k] (k<200) | W_ih[j][k-224] (224<=k<252) | 0
    s8v Af[7][8];
    #pragma unroll
    for (int u = 0; u < 7; ++u) {
        const int j = 16 * (first + u) + lr;
        #pragma unroll
        for (int kc = 0; kc < 8; ++kc) {
            union { short s[8]; s8v v; } tv;
            #pragma unroll
            for (int i = 0; i < 8; ++i) {
                const int k = 32 * kc + 8 * q + i;
                float w = 0.0f;
                if (u < cnt && j < HH) {
                    if (k < HH)                    w = W_hh[j * HH + k];
                    else if (k >= KX && k < KX+II) w = W_ih[j * II + (k - KX)];
                }
                tv.s[i] = f2bf(w);
            }
            Af[u][kc] = tv.v;
        }
    }

    // per-lane bias as MFMA C-init (C rows j = 16*jt + 4*q + i)
    f4v biasv[7];
    #pragma unroll
    for (int u = 0; u < 7; ++u) {
        f4v bv = {0.f, 0.f, 0.f, 0.f};
        #pragma unroll
        for (int i = 0; i < 4; ++i) {
            const int j = 16 * (first + u) + 4 * q + i;
            if (u < cnt && j < HH) bv[i] = b_ih[j] + b_hh[j];
        }
        biasv[u] = bv;
    }

    // ---- x pipeline: lane (lr,q) holds x[b0+lr][t][8q..8q+7] (cols>=28 -> 0) ----
    const float* xp = x + (long)(b0 + lr) * (TT * II) + 8 * q;
    f4v xa0 = {0,0,0,0}, xb0 = {0,0,0,0}, xa1 = {0,0,0,0}, xb1 = {0,0,0,0};
    xa0 = *(const f4v*)(xp);
    if (q != 3) xb0 = *(const f4v*)(xp + 4);
    xa1 = *(const f4v*)(xp + II);
    if (q != 3) xb1 = *(const f4v*)(xp + II + 4);

    __syncthreads();   // zeroed Hs visible

    auto step = [&](int t, int pb, f4v& xa, f4v& xb) {
        // x B-frag from registers, then reissue this slot's load for t+2
        union { int i4[4]; s8v v; } xf;
        xf.i4[0] = pk_bf16(xa.x, xa.y);
        xf.i4[1] = pk_bf16(xa.z, xa.w);
        xf.i4[2] = pk_bf16(xb.x, xb.y);
        xf.i4[3] = pk_bf16(xb.z, xb.w);
        {
            const int tn = (t + 2 < TT) ? t + 2 : TT - 1;
            xa = *(const f4v*)(xp + tn * II);
            if (q != 3) xb = *(const f4v*)(xp + tn * II + 4);
        }

        // all 7 h B-frags up front (independent ds_read_b128s)
        s8v bf[7];
        #pragma unroll
        for (int kc = 0; kc < 7; ++kc)
            bf[kc] = *(const s8v*)&Hs[pb][lr][32 * kc + 8 * q];

        // u-outer: early tiles retire early -> cvt/write overlaps later MFMA
        #pragma unroll
        for (int u = 0; u < 7; ++u) {
            if (u < cnt) {
                const int jt = first + u;
                // x-chunk first (register-fed, C = bias), then the 7 h-chunks
                f4v acc = __builtin_amdgcn_mfma_f32_16x16x32_bf16(Af[u][7], xf.v, biasv[u], 0, 0, 0);
                #pragma unroll
                for (int kc = 0; kc < 7; ++kc)
                    acc = __builtin_amdgcn_mfma_f32_16x16x32_bf16(Af[u][kc], bf[kc], acc, 0, 0, 0);

                const float r0 = fmaxf(acc.x, 0.f), r1 = fmaxf(acc.y, 0.f);
                const float r2 = fmaxf(acc.z, 0.f), r3 = fmaxf(acc.w, 0.f);
                int2 hv;
                hv.x = pk_bf16(r0, r1);
                hv.y = pk_bf16(r2, r3);
                *(int2*)&Hs[pb ^ 1][lr][16 * jt + 4 * q] = hv;   // 8B store, 2-way max -> free
                if (t == TT - 1) {
                    f4v rf = {r0, r1, r2, r3};
                    *(f4v*)&Hf[lr][16 * jt + 4 * q] = rf;
                }
            }
        }
        __syncthreads();   // partner's writes visible; WAR on pb safe (its reads retired pre-barrier)
    };

    for (int tb = 0; tb < TT; tb += 2) {
        step(tb,     0, xa0, xb0);
        step(tb + 1, 1, xa1, xb1);
    }

    // ---- FC epilogue (fp32): out[b][o] = h_T . W_fc[o] + b_fc[o] ----
    for (int i = tid; i < BB * 10; i += NT) {
        const int o = i >> 4, r = i & 15;
        float s = b_fc[o];
        for (int k = 0; k < HH; ++k)
            s = fmaf(Hf[r][k], W_fc[o * HH + k], s);
        __builtin_nontemporal_store(s, &out[(long)(b0 + r) * 10 + o]);
    }
}

extern "C" void kernel_launch(void* const* d_in, const int* in_sizes, int n_in,
                              void* d_out, int out_size, void* d_ws, size_t ws_size,
                              hipStream_t stream) {
    const float* x    = (const float*)d_in[0];
    const float* W_ih = (const float*)d_in[1];
    const float* W_hh = (const float*)d_in[2];
    const float* b_ih = (const float*)d_in[3];
    const float* b_hh = (const float*)d_in[4];
    const float* W_fc = (const float*)d_in[5];
    const float* b_fc = (const float*)d_in[6];
    float* out = (float*)d_out;

    rnn_w2<<<dim3(8192 / BB), dim3(NT), 0, stream>>>(
        x, W_ih, W_hh, b_ih, b_hh, W_fc, b_fc, out);
}